// Round 19
// baseline (107.846 us; speedup 1.0000x reference)
//
#include <hip/hip_runtime.h>
#include <hip/hip_fp16.h>

#define D_ 160
#define H_ 192
#define W_ 160
#define PLANE (H_*W_)          // 30720
#define VOL (D_*PLANE)         // 4915200 per sample (per quantity)
#define NS 2
#define WSZ 729.0f
#define DCH 40                 // d-outputs per k_d block (proven optimal: 1.2x reads)
#define TILE 512               // halves of the (h,w) plane per k_d block

// B per sample: 5 quantities (I, J, I*I, J*J, I*J), each VOL fp16,
// layout [q][d][h][w].

__global__ void k_zero(float* acc) {
    if (threadIdx.x < NS) acc[threadIdx.x] = 0.f;
}

// ---------------- pass 1: products + W-sum + H-sum -> fp16 B ----------------
// Proven version VERBATIM (r8/r11/r17/r18: 63-66 us, FETCH ~= compulsory,
// VGPR 36): thread = 4 w (seg) x 8 h (chunk) x fixed d, 256-thr blocks.
// per sample: seg(40) x chunk(24) x d(160) = 153600 threads = 600 blocks
__global__ __launch_bounds__(256) void k_wh(const float* __restrict__ I,
                                            const float* __restrict__ J,
                                            __half* __restrict__ B, long stride) {
    int b  = blockIdx.x;
    int sl = b / 600;
    int t  = (b % 600) * 256 + threadIdx.x;     // 0..153599
    int seg   = t % 40;
    int chunk = (t / 40) % 24;
    int d     = t / 960;                        // 0..159
    int w0 = seg * 4;
    int h0 = chunk * 8;
    const float* Ib = I + (long)sl * VOL + (long)d * PLANE;
    const float* Jb = J + (long)sl * VOL + (long)d * PLANE;
    __half* Bb = B + (long)sl * stride + (long)d * PLANE + w0;   // + q*VOL + h*W_

    float rs[5][4];
#pragma unroll
    for (int q = 0; q < 5; ++q)
#pragma unroll
        for (int k = 0; k < 4; ++k) rs[q][k] = 0.f;

    // one row's W-window sums (4 outputs) for all 5 quantities, signed accumulate
    auto rowop = [&](int h, float sign) {
        if (h < 0 || h >= H_) return;
        const float* ri = Ib + (long)h * W_;
        const float* rj = Jb + (long)h * W_;
        float vI[12], vJ[12];
#pragma unroll
        for (int bq = 0; bq < 3; ++bq) {
            int f0 = w0 - 4 + 4 * bq;           // multiple of 4 -> aligned
            if (f0 >= 0 && f0 <= W_ - 4) {
                float4 a = *reinterpret_cast<const float4*>(ri + f0);
                float4 c = *reinterpret_cast<const float4*>(rj + f0);
                vI[4*bq+0]=a.x; vI[4*bq+1]=a.y; vI[4*bq+2]=a.z; vI[4*bq+3]=a.w;
                vJ[4*bq+0]=c.x; vJ[4*bq+1]=c.y; vJ[4*bq+2]=c.z; vJ[4*bq+3]=c.w;
            } else {
#pragma unroll
                for (int k = 0; k < 4; ++k) { vI[4*bq+k] = 0.f; vJ[4*bq+k] = 0.f; }
            }
        }
#pragma unroll
        for (int q = 0; q < 5; ++q) {
            float p[12];
#pragma unroll
            for (int i = 0; i < 12; ++i) {
                float a = vI[i], bb = vJ[i];
                p[i] = (q == 0) ? a : (q == 1) ? bb : (q == 2) ? a*a : (q == 3) ? bb*bb : a*bb;
            }
            float o[4];
            float ssum = 0.f;
#pragma unroll
            for (int i = 0; i < 9; ++i) ssum += p[i];
            o[0] = ssum;
#pragma unroll
            for (int k = 1; k < 4; ++k) { ssum += p[k + 8] - p[k - 1]; o[k] = ssum; }
#pragma unroll
            for (int k = 0; k < 4; ++k) rs[q][k] += sign * o[k];
        }
    };

    // init window rows [h0-4, h0+3]
    for (int i = 0; i < 8; ++i) rowop(h0 - 4 + i, 1.f);

    for (int hh = 0; hh < 8; ++hh) {
        int h = h0 + hh;
        rowop(h + 4, 1.f);                       // window now [h-4, h+4]
#pragma unroll
        for (int q = 0; q < 5; ++q) {
            union { __half hv[4]; uint2 v; } u;
#pragma unroll
            for (int k = 0; k < 4; ++k) u.hv[k] = __float2half(rs[q][k]);
            *reinterpret_cast<uint2*>(Bb + (long)q * VOL + (long)h * W_) = u.v;  // 8B store
        }
        rowop(h - 4, -1.f);                      // prep next: [h-3, h+4]
    }
}

// ---------------- pass 2: D-axis 9-box-sum via LDS ring + cc ----------------
// r12 structure (DCH=40, TILE=512, 12-slot ring, 1 barrier/step) with ONE
// change: PREFETCH DEPTH 2 (each wave holds cur+nxt plane loads). Doubles
// bytes-in-flight 2.4 -> 4.8 MB to cover the ~500 ns latency at 6.3 TB/s
// (BW = inflight/latency model; r17 showed time is bytes-proportional).
// blocks: 2 samples x 4 chunks x 60 tiles = 480
__device__ __forceinline__ float ccf(float Is, float Js, float I2, float J2, float IJ) {
    float uI = Is * (1.f / WSZ), uJ = Js * (1.f / WSZ);
    float cross = IJ - uJ * Is - uI * Js + uI * uJ * WSZ;
    float Iv = I2 - 2.f * uI * Is + uI * uI * WSZ;
    float Jv = J2 - 2.f * uJ * Js + uJ * uJ * WSZ;
    return 1.f - cross * cross / (Iv * Jv + 1e-5f);
}

__global__ __launch_bounds__(256) void k_d(const __half* __restrict__ B,
                                           float* __restrict__ acc, long stride) {
    __shared__ __half ring[12][5][TILE];        // 61.4 KB -> 2 blocks/CU
    __shared__ float red[256];
    int b   = blockIdx.x;
    int sl  = b / 240;
    int r   = b % 240;
    int chunk = r / 60;                         // 0..3
    int tile  = r % 60;                         // fast index: neighbors stream together
    int c0 = chunk * DCH;
    long tile0 = (long)tile * TILE;
    int tid = threadIdx.x;
    int q0 = tid >> 6;                          // wave index -> quantity 0..3
    int g0 = tid & 63;
    bool two = (tid < 64);                      // wave 0 also loads q=4
    const __half* Bs = B + (long)sl * stride;

    int4 z; z.x = z.y = z.z = z.w = 0;
    auto ld = [&](int q, int g, int dp) -> int4 {
        if (dp < 0 || dp >= D_) return z;
        return *reinterpret_cast<const int4*>(Bs + (long)q * VOL + (long)dp * PLANE + tile0 + g * 8);
    };

    float s[5][2];
#pragma unroll
    for (int q = 0; q < 5; ++q) { s[q][0] = 0.f; s[q][1] = 0.f; }

    // depth-2 prologue: planes c0-4 (cur) and c0-3 (nxt) in flight
    int4 v0c = ld(q0, g0, c0 - 4);
    int4 v1c = two ? ld(4, tid, c0 - 4) : z;
    int4 v0n = ld(q0, g0, c0 - 3);
    int4 v1n = two ? ld(4, tid, c0 - 3) : z;

    float local = 0.f;
    for (int i = 0; i < DCH + 8; ++i) {         // dp = c0-4 .. c0+43
        int dp = c0 - 4 + i;
        int slot = (dp + 16) % 12;              // dp >= -4 -> nonneg
        *reinterpret_cast<int4*>(&ring[slot][q0][g0 * 8]) = v0c;
        if (two) *reinterpret_cast<int4*>(&ring[slot][4][tid * 8]) = v1c;
        v0c = v0n; v1c = v1n;
        if (i < DCH + 6) {                      // issue plane dp+2 (2-deep pipeline)
            v0n = ld(q0, g0, dp + 2);
            if (two) v1n = ld(4, tid, dp + 2);
        }
        __syncthreads();
        int so = (dp + 7) % 12;                 // (dp-9+16)%12
        bool dosub = (dp - 9 >= c0 - 4);
#pragma unroll
        for (int q = 0; q < 5; ++q) {
            __half2 hn = *reinterpret_cast<const __half2*>(&ring[slot][q][2 * tid]);
            float2 fn = __half22float2(hn);
            s[q][0] += fn.x; s[q][1] += fn.y;
            if (dosub) {
                __half2 ho = *reinterpret_cast<const __half2*>(&ring[so][q][2 * tid]);
                float2 fo = __half22float2(ho);
                s[q][0] -= fo.x; s[q][1] -= fo.y;
            }
        }
        int dout = dp - 4;
        if (dout >= c0 && dout < c0 + DCH) {
            local += ccf(s[0][0], s[1][0], s[2][0], s[3][0], s[4][0]);
            local += ccf(s[0][1], s[1][1], s[2][1], s[3][1], s[4][1]);
        }
        // no second barrier: write(dp+1) slot is at ring distance {1,11} from
        // read slots {dp, dp-9}; one-step skew bounded by the barrier
    }

    red[tid] = local;
    __syncthreads();
    for (int off = 128; off > 0; off >>= 1) {
        if (tid < off) red[tid] += red[tid + off];
        __syncthreads();
    }
    if (tid == 0) atomicAdd(acc + sl, red[0]);
}

__global__ void k_fin(const float* __restrict__ acc, float* __restrict__ out) {
    if (threadIdx.x < NS) out[threadIdx.x] = acc[threadIdx.x] * (1.f / (float)VOL);
}

extern "C" void kernel_launch(void* const* d_in, const int* in_sizes, int n_in,
                              void* d_out, int out_size, void* d_ws, size_t ws_size,
                              hipStream_t stream) {
    const float* J = (const float*)d_in[0];   // y_pred
    const float* I = (const float*)d_in[1];   // y_true
    float* out = (float*)d_out;
    __half* B  = (__half*)d_ws;               // 2 samples x 5*VOL fp16 = 98.3 MB

    const long SAMP = 5L * VOL;
    float* acc = (float*)((char*)d_ws + (size_t)(NS * SAMP) * sizeof(__half));

    k_zero<<<1, 64, 0, stream>>>(acc);
    k_wh<<<NS * 600, 256, 0, stream>>>(I, J, B, SAMP);
    k_d<<<480, 256, 0, stream>>>(B, acc, SAMP);
    k_fin<<<1, 64, 0, stream>>>(acc, out);
}

// Round 20
// 93.629 us; speedup vs baseline: 1.1518x; 1.1518x over previous
//
#include <hip/hip_runtime.h>
#include <hip/hip_fp16.h>

#define D_ 160
#define H_ 192
#define W_ 160
#define PLANE (H_*W_)          // 30720
#define VOL (D_*PLANE)         // 4915200 per sample (per quantity)
#define NS 2
#define WSZ 729.0f
#define DCH 40                 // d-outputs per k_d block (proven optimal: 1.2x reads)
#define TILE 512               // halves of the (h,w) plane per k_d block

// B per sample: 5 quantities (I, J, I*I, J*J, I*J), each VOL fp16,
// layout [q][d][h][w].
//
// FINAL COMPOSITION (= round-12 best, 93.8 us):
//  k_wh: 64 us, FETCH 87 MB ~= compulsory, VALU 45% / HBM 37% balanced.
//        8 structural variants (r5,r6,r9,r10,r13,r14,r15,r16) all regressed:
//        h-splits & q-splits inflate FETCH (L2 does not absorb cross-block
//        re-reads); pairing/128-thr raise VGPR or thrash L1. Converged.
//  k_d:  28 us, reads 118 MB (1.2x minimal) at ~4.2 TB/s = this pattern's
//        L3-path ceiling with a per-step barrier: bytes-proportional (r17),
//        parallelism-insensitive (r11/r17), issue-balance-insensitive (r18),
//        prefetch-depth-insensitive (r19: vmcnt(0) drain before s_barrier
//        forces per-step completion). Converged.

__global__ void k_zero(float* acc) {
    if (threadIdx.x < NS) acc[threadIdx.x] = 0.f;
}

// ---------------- pass 1: products + W-sum + H-sum -> fp16 B ----------------
// thread: 4 w (seg) x 8 h-outputs (chunk) x fixed d; 256-thr blocks.
// Running H-sums rs[5][4] in fp32; entering/leaving rows recomputed from the
// fp32 inputs (recompute-subtract: bit-identical -> exact cancellation).
// per sample: seg(40) x chunk(24) x d(160) = 153600 threads = 600 blocks
__global__ __launch_bounds__(256) void k_wh(const float* __restrict__ I,
                                            const float* __restrict__ J,
                                            __half* __restrict__ B, long stride) {
    int b  = blockIdx.x;
    int sl = b / 600;
    int t  = (b % 600) * 256 + threadIdx.x;     // 0..153599
    int seg   = t % 40;
    int chunk = (t / 40) % 24;
    int d     = t / 960;                        // 0..159
    int w0 = seg * 4;
    int h0 = chunk * 8;
    const float* Ib = I + (long)sl * VOL + (long)d * PLANE;
    const float* Jb = J + (long)sl * VOL + (long)d * PLANE;
    __half* Bb = B + (long)sl * stride + (long)d * PLANE + w0;   // + q*VOL + h*W_

    float rs[5][4];
#pragma unroll
    for (int q = 0; q < 5; ++q)
#pragma unroll
        for (int k = 0; k < 4; ++k) rs[q][k] = 0.f;

    // one row's W-window sums (4 outputs) for all 5 quantities, signed accumulate
    auto rowop = [&](int h, float sign) {
        if (h < 0 || h >= H_) return;
        const float* ri = Ib + (long)h * W_;
        const float* rj = Jb + (long)h * W_;
        float vI[12], vJ[12];
#pragma unroll
        for (int bq = 0; bq < 3; ++bq) {
            int f0 = w0 - 4 + 4 * bq;           // multiple of 4 -> aligned
            if (f0 >= 0 && f0 <= W_ - 4) {
                float4 a = *reinterpret_cast<const float4*>(ri + f0);
                float4 c = *reinterpret_cast<const float4*>(rj + f0);
                vI[4*bq+0]=a.x; vI[4*bq+1]=a.y; vI[4*bq+2]=a.z; vI[4*bq+3]=a.w;
                vJ[4*bq+0]=c.x; vJ[4*bq+1]=c.y; vJ[4*bq+2]=c.z; vJ[4*bq+3]=c.w;
            } else {
#pragma unroll
                for (int k = 0; k < 4; ++k) { vI[4*bq+k] = 0.f; vJ[4*bq+k] = 0.f; }
            }
        }
#pragma unroll
        for (int q = 0; q < 5; ++q) {
            float p[12];
#pragma unroll
            for (int i = 0; i < 12; ++i) {
                float a = vI[i], bb = vJ[i];
                p[i] = (q == 0) ? a : (q == 1) ? bb : (q == 2) ? a*a : (q == 3) ? bb*bb : a*bb;
            }
            float o[4];
            float ssum = 0.f;
#pragma unroll
            for (int i = 0; i < 9; ++i) ssum += p[i];
            o[0] = ssum;
#pragma unroll
            for (int k = 1; k < 4; ++k) { ssum += p[k + 8] - p[k - 1]; o[k] = ssum; }
#pragma unroll
            for (int k = 0; k < 4; ++k) rs[q][k] += sign * o[k];
        }
    };

    // init window rows [h0-4, h0+3]
    for (int i = 0; i < 8; ++i) rowop(h0 - 4 + i, 1.f);

    for (int hh = 0; hh < 8; ++hh) {
        int h = h0 + hh;
        rowop(h + 4, 1.f);                       // window now [h-4, h+4]
#pragma unroll
        for (int q = 0; q < 5; ++q) {
            union { __half hv[4]; uint2 v; } u;
#pragma unroll
            for (int k = 0; k < 4; ++k) u.hv[k] = __float2half(rs[q][k]);
            *reinterpret_cast<uint2*>(Bb + (long)q * VOL + (long)h * W_) = u.v;  // 8B store
        }
        rowop(h - 4, -1.f);                      // prep next: [h-3, h+4]
    }
}

// ---------------- pass 2: D-axis 9-box-sum via LDS ring + cc ----------------
// Block: 256 thr, (h,w)-tile of 512 halves, d-chunk of 40 (+9 halo = 1.2x reads).
// Per dp step: waves 0-3 load q=0..3 plane slices (64 int4 = 1 KB contiguous
// each), wave 0 also loads q=4; slices go into a 12-slot LDS ring. Each thread
// keeps fp32 running sums s[5][2] for 2 outputs: add new slice, subtract the
// slice from 9 steps ago out of LDS (bit-identical -> exact cancel).
// Ring depth 12 + one barrier/step is hazard-free: write(k+1) slot is at ring
// distance {1,11} from read slots {k, k-10} -- never equal; barrier bounds
// wave skew to one step.
// blocks: 2 samples x 4 chunks x 60 tiles = 480
__device__ __forceinline__ float ccf(float Is, float Js, float I2, float J2, float IJ) {
    float uI = Is * (1.f / WSZ), uJ = Js * (1.f / WSZ);
    float cross = IJ - uJ * Is - uI * Js + uI * uJ * WSZ;
    float Iv = I2 - 2.f * uI * Is + uI * uI * WSZ;
    float Jv = J2 - 2.f * uJ * Js + uJ * uJ * WSZ;
    return 1.f - cross * cross / (Iv * Jv + 1e-5f);
}

__global__ __launch_bounds__(256) void k_d(const __half* __restrict__ B,
                                           float* __restrict__ acc, long stride) {
    __shared__ __half ring[12][5][TILE];        // 61.4 KB -> 2 blocks/CU
    __shared__ float red[256];
    int b   = blockIdx.x;
    int sl  = b / 240;
    int r   = b % 240;
    int chunk = r / 60;                         // 0..3
    int tile  = r % 60;                         // fast index: neighbors stream together
    int c0 = chunk * DCH;
    long tile0 = (long)tile * TILE;
    int tid = threadIdx.x;
    int q0 = tid >> 6;                          // wave index -> quantity 0..3
    int g0 = tid & 63;
    bool two = (tid < 64);                      // wave 0 also loads q=4
    const __half* Bs = B + (long)sl * stride;

    int4 z; z.x = z.y = z.z = z.w = 0;
    auto ld = [&](int q, int g, int dp) -> int4 {
        if (dp < 0 || dp >= D_) return z;
        return *reinterpret_cast<const int4*>(Bs + (long)q * VOL + (long)dp * PLANE + tile0 + g * 8);
    };

    float s[5][2];
#pragma unroll
    for (int q = 0; q < 5; ++q) { s[q][0] = 0.f; s[q][1] = 0.f; }

    int4 v0 = ld(q0, g0, c0 - 4);
    int4 v1 = two ? ld(4, tid, c0 - 4) : z;

    float local = 0.f;
    for (int i = 0; i < DCH + 8; ++i) {         // dp = c0-4 .. c0+43
        int dp = c0 - 4 + i;
        int slot = (dp + 16) % 12;              // dp >= -4 -> nonneg
        *reinterpret_cast<int4*>(&ring[slot][q0][g0 * 8]) = v0;
        if (two) *reinterpret_cast<int4*>(&ring[slot][4][tid * 8]) = v1;
        if (i < DCH + 7) {                      // prefetch next plane
            v0 = ld(q0, g0, dp + 1);
            if (two) v1 = ld(4, tid, dp + 1);
        }
        __syncthreads();
        int so = (dp + 7) % 12;                 // (dp-9+16)%12
        bool dosub = (dp - 9 >= c0 - 4);
#pragma unroll
        for (int q = 0; q < 5; ++q) {
            __half2 hn = *reinterpret_cast<const __half2*>(&ring[slot][q][2 * tid]);
            float2 fn = __half22float2(hn);
            s[q][0] += fn.x; s[q][1] += fn.y;
            if (dosub) {
                __half2 ho = *reinterpret_cast<const __half2*>(&ring[so][q][2 * tid]);
                float2 fo = __half22float2(ho);
                s[q][0] -= fo.x; s[q][1] -= fo.y;
            }
        }
        int dout = dp - 4;
        if (dout >= c0 && dout < c0 + DCH) {
            local += ccf(s[0][0], s[1][0], s[2][0], s[3][0], s[4][0]);
            local += ccf(s[0][1], s[1][1], s[2][1], s[3][1], s[4][1]);
        }
        // no second barrier: ring-depth-12 slot analysis makes write(k+1)
        // disjoint from any slot still being read at step k
    }

    red[tid] = local;
    __syncthreads();
    for (int off = 128; off > 0; off >>= 1) {
        if (tid < off) red[tid] += red[tid + off];
        __syncthreads();
    }
    if (tid == 0) atomicAdd(acc + sl, red[0]);
}

__global__ void k_fin(const float* __restrict__ acc, float* __restrict__ out) {
    if (threadIdx.x < NS) out[threadIdx.x] = acc[threadIdx.x] * (1.f / (float)VOL);
}

extern "C" void kernel_launch(void* const* d_in, const int* in_sizes, int n_in,
                              void* d_out, int out_size, void* d_ws, size_t ws_size,
                              hipStream_t stream) {
    const float* J = (const float*)d_in[0];   // y_pred
    const float* I = (const float*)d_in[1];   // y_true
    float* out = (float*)d_out;
    __half* B  = (__half*)d_ws;               // 2 samples x 5*VOL fp16 = 98.3 MB

    const long SAMP = 5L * VOL;
    float* acc = (float*)((char*)d_ws + (size_t)(NS * SAMP) * sizeof(__half));

    k_zero<<<1, 64, 0, stream>>>(acc);
    k_wh<<<NS * 600, 256, 0, stream>>>(I, J, B, SAMP);
    k_d<<<480, 256, 0, stream>>>(B, acc, SAMP);
    k_fin<<<1, 64, 0, stream>>>(acc, out);
}